// Round 5
// baseline (2735.772 us; speedup 1.0000x reference)
//
#include <hip/hip_runtime.h>
#include <hip/hip_bf16.h>

#define DH 20            // hidden width
#define SCAN_CHUNKS 1024

// ---------------- setup kernels ----------------

// deg arrays are zeroed by hipMemsetAsync; counts EXCLUDE self-loop.
__global__ void count_deg(const int* __restrict__ src, const int* __restrict__ dst,
                          int* __restrict__ out_deg, int* __restrict__ in_deg, int E) {
    int e = blockIdx.x * blockDim.x + threadIdx.x;
    if (e < E) {
        atomicAdd(&out_deg[src[e]], 1);
        atomicAdd(&in_deg[dst[e]], 1);
    }
}

// norm = (deg+1)^-1/2  (self-loop included here)
__global__ void compute_norm(const int* __restrict__ out_deg, const int* __restrict__ in_deg,
                             double* __restrict__ dout, double* __restrict__ din, int n) {
    int i = blockIdx.x * blockDim.x + threadIdx.x;
    if (i < n) {
        dout[i] = 1.0 / sqrt((double)(out_deg[i] + 1));
        din[i]  = 1.0 / sqrt((double)(in_deg[i] + 1));
    }
}

// ---- parallel row_ptr build: chunk sums -> scan -> fill ----

__global__ void chunk_sums(const int* __restrict__ in_deg, int* __restrict__ cs, int n_nodes) {
    int w    = (blockIdx.x * blockDim.x + threadIdx.x) >> 6;   // wave = chunk
    int lane = threadIdx.x & 63;
    if (w >= SCAN_CHUNKS) return;
    int chunk = (n_nodes + SCAN_CHUNKS - 1) / SCAN_CHUNKS;
    int lo = w * chunk;
    int hi = lo + chunk; if (hi > n_nodes) hi = n_nodes;
    int s = 0;
    for (int i = lo + lane; i < hi; i += 64) s += in_deg[i];
#pragma unroll
    for (int off = 32; off; off >>= 1) s += __shfl_xor(s, off, 64);
    if (lane == 0) cs[w] = s;
}

__global__ void scan_chunks(int* __restrict__ cs) {
    __shared__ int lds[SCAN_CHUNKS];
    int t = threadIdx.x;
    int v = cs[t];
    lds[t] = v;
    __syncthreads();
    for (int off = 1; off < SCAN_CHUNKS; off <<= 1) {
        int u = (t >= off) ? lds[t - off] : 0;
        __syncthreads();
        lds[t] += u;
        __syncthreads();
    }
    cs[t] = lds[t] - v;   // exclusive prefix
}

__global__ void fill_rowptr(const int* __restrict__ in_deg, const int* __restrict__ cs,
                            int* __restrict__ row_ptr, int* __restrict__ cursor,
                            int n_nodes, int n_edges) {
    int w    = (blockIdx.x * blockDim.x + threadIdx.x) >> 6;   // wave = chunk
    int lane = threadIdx.x & 63;
    if (w >= SCAN_CHUNKS) return;
    int chunk = (n_nodes + SCAN_CHUNKS - 1) / SCAN_CHUNKS;
    int lo = w * chunk;
    int hi = lo + chunk; if (hi > n_nodes) hi = n_nodes;
    int run = cs[w];
    for (int base = lo; base < hi; base += 64) {
        int i = base + lane;
        int d = (i < hi) ? in_deg[i] : 0;
        int incl = d;
#pragma unroll
        for (int off = 1; off < 64; off <<= 1) {
            int t = __shfl_up(incl, off, 64);
            if (lane >= off) incl += t;
        }
        int excl = run + incl - d;
        if (i < hi) { row_ptr[i] = excl; cursor[i] = excl; }
        run += __shfl(incl, 63, 64);
    }
    if (w == 0 && lane == 0) row_ptr[n_nodes] = n_edges;
}

__global__ void fill_csr(const int* __restrict__ src, const int* __restrict__ dst,
                         int* __restrict__ cursor, int* __restrict__ col, int E) {
    int e = blockIdx.x * blockDim.x + threadIdx.x;
    if (e < E) {
        int slot = atomicAdd(&cursor[dst[e]], 1);
        col[slot] = src[e];
    }
}

// ---------------- layer kernels (aggregate-first, 1 wave per node) ----------------

// x0[n] = feat[n] * dout[n]   (layer 0 input is N x 1)
__global__ void compute_x0(const float* __restrict__ feat, const double* __restrict__ dout,
                           double* __restrict__ x0, int n) {
    int i = blockIdx.x * blockDim.x + threadIdx.x;
    if (i < n) x0[i] = (double)feat[i] * dout[i];
}

// layer 0: g[n] = x0[n] + sum_{s in N(n)} x0[s]  (scalar gather, 64 lanes edge-parallel)
__global__ __launch_bounds__(256) void layer_start(
        const double* __restrict__ x0, const int* __restrict__ row_ptr,
        const int* __restrict__ col, const double* __restrict__ din,
        const double* __restrict__ dout, const float* __restrict__ W,
        const float* __restrict__ b, float* __restrict__ xout, int n_nodes) {
    int n    = (blockIdx.x * blockDim.x + threadIdx.x) >> 6;   // one wave per node
    int lane = threadIdx.x & 63;
    if (n >= n_nodes) return;
    n = __builtin_amdgcn_readfirstlane(n);
    double a = (lane == 0) ? x0[n] : 0.0;   // self loop
    int e0 = row_ptr[n], e1 = row_ptr[n + 1];
    for (int e = e0 + lane; e < e1; e += 64)
        a += x0[__builtin_nontemporal_load(&col[e])];
#pragma unroll
    for (int off = 32; off > 0; off >>= 1)
        a += __shfl_xor(a, off, 64);
    if (lane < DH) {
        double v = a * din[n] * (double)W[lane] + (double)b[lane];
        float r = fmaxf((float)v, 0.0f);
        xout[(long)n * DH + lane] = (float)((double)r * dout[n]);
    }
}

// mid/final layers: one wave per node, batch gather.
// lane = 5*ep + jq,  ep in [0,12) = edge slot, jq in [0,5) = float4 quarter of the row.
// One coalesced col load covers up to 64 edges; indices distributed by shfl; 4
// PREDICATED gathers per lane cover 48 edges (exec-masked: invalid slots issue
// no L1 probe and contribute exact 0); rare deg>48 tail loops.
__global__ __launch_bounds__(256, 8) void layer_mid(
        const float* __restrict__ x, const int* __restrict__ row_ptr,
        const int* __restrict__ col, const double* __restrict__ din,
        const double* __restrict__ dout, const float* __restrict__ W,
        const float* __restrict__ b, float* __restrict__ xout,
        int n_nodes, int mode) {
    __shared__ float Wl[DH * DH];
    for (int i = threadIdx.x; i < DH * DH; i += blockDim.x) Wl[i] = W[i];
    __syncthreads();

    int n    = (blockIdx.x * blockDim.x + threadIdx.x) >> 6;   // one wave per node
    int lane = threadIdx.x & 63;
    if (n >= n_nodes) return;
    n = __builtin_amdgcn_readfirstlane(n);     // wave-uniform -> scalar loads below

    int ep = lane / 5;           // edge slot 0..12 (lanes 60..63 -> ep=12, inactive)
    int jq = lane - ep * 5;      // float4 quarter 0..4
    const float4* __restrict__ x4 = (const float4*)x;   // row n = x4[n*5 .. n*5+4]

    int e0 = row_ptr[n], e1 = row_ptr[n + 1];  // scalar s_load

    // one coalesced col load: lane <-> edge position e0+lane
    int epos = e0 + lane;
    int ci = -1;
    if (epos < e1) ci = __builtin_nontemporal_load(&col[epos]);

    // distribute indices to edge slots: slot ep takes positions ep, ep+12, ep+24, ep+36
    int s0 = __shfl(ci, ep, 64);
    int s1 = __shfl(ci, ep + 12, 64);
    int s2 = __shfl(ci, ep + 24, 64);
    int s3 = __shfl(ci, ep + 36, 64);
    bool p0 = (ep < 12) && (s0 >= 0);
    bool p1 = (ep < 12) && (s1 >= 0);
    bool p2 = (ep < 12) && (s2 >= 0);
    bool p3 = (ep < 12) && (s3 >= 0);

    float4 z = {0.0f, 0.0f, 0.0f, 0.0f};
    float4 v0 = z, v1 = z, v2 = z, v3 = z, vs = z;
    if (p0) v0 = x4[(size_t)s0 * 5 + jq];
    if (p1) v1 = x4[(size_t)s1 * 5 + jq];
    if (p2) v2 = x4[(size_t)s2 * 5 + jq];
    if (p3) v3 = x4[(size_t)s3 * 5 + jq];
    if (ep == 0) vs = x4[(size_t)n * 5 + jq];   // self loop on slot 0

    double g[4];
    g[0] = (double)vs.x + (double)v0.x + (double)v1.x + (double)v2.x + (double)v3.x;
    g[1] = (double)vs.y + (double)v0.y + (double)v1.y + (double)v2.y + (double)v3.y;
    g[2] = (double)vs.z + (double)v0.z + (double)v1.z + (double)v2.z + (double)v3.z;
    g[3] = (double)vs.w + (double)v0.w + (double)v1.w + (double)v2.w + (double)v3.w;

    // rare tail: deg > 48 (wave-uniform branch)
    if (e1 - e0 > 48) {
        if (ep < 12) {
            for (int e = e0 + 48 + ep; e < e1; e += 12) {
                int s = __builtin_nontemporal_load(&col[e]);
                float4 v = x4[(size_t)s * 5 + jq];
                g[0] += (double)v.x; g[1] += (double)v.y;
                g[2] += (double)v.z; g[3] += (double)v.w;
            }
        }
    }

    // fold 12 edge slots down to slot 0 (lanes 0..4 hold g[0..3] = features 4*jq..4*jq+3)
#define FOLD(LIM, DELTA)                                                        \
    {                                                                           \
        int srcl = lane + DELTA; if (srcl > 63) srcl = lane;                    \
        double t0 = __shfl(g[0], srcl, 64);                                     \
        double t1 = __shfl(g[1], srcl, 64);                                     \
        double t2 = __shfl(g[2], srcl, 64);                                     \
        double t3 = __shfl(g[3], srcl, 64);                                     \
        if (ep < (LIM)) { g[0] += t0; g[1] += t1; g[2] += t2; g[3] += t3; }     \
    }
    FOLD(4, 40)   // ep(0..3)  += ep+8
    FOLD(4, 20)   // ep(0..3)  += ep+4
    FOLD(2, 10)   // ep(0..1)  += ep+2
    FOLD(1, 5)    // ep(0)     += ep+1
#undef FOLD

    // cross-lane matvec: out_j = sum_k g_k * W[k][j];  g_k lives at lane k>>2, reg k&3
    int jj = (lane < DH) ? lane : 0;
    double acc = 0.0;
#pragma unroll
    for (int k = 0; k < DH; ++k) {
        double gk = __shfl(g[k & 3], k >> 2, 64);
        acc += gk * (double)Wl[k * DH + jj];
    }

    if (lane < DH) {
        double v = acc * din[n] + (double)b[lane];
        if (mode == 0) {
            float r = fmaxf((float)v, 0.0f);
            xout[(long)n * DH + lane] = (float)((double)r * dout[n]);
        } else {
            xout[(long)n * DH + lane] = (float)v;
        }
    }
}

// ---------------- launch ----------------

static inline size_t align256(size_t x) { return (x + 255) & ~(size_t)255; }

extern "C" void kernel_launch(void* const* d_in, const int* in_sizes, int n_in,
                              void* d_out, int out_size, void* d_ws, size_t ws_size,
                              hipStream_t stream) {
    const float* feat    = (const float*)d_in[0];
    const float* W_start = (const float*)d_in[1];
    const float* b_start = (const float*)d_in[2];
    const float* W_mid   = (const float*)d_in[3];
    const float* b_mid   = (const float*)d_in[4];
    const float* W_final = (const float*)d_in[5];
    const float* b_final = (const float*)d_in[6];
    const int*   src     = (const int*)d_in[7];
    const int*   dst     = (const int*)d_in[8];

    const int N = in_sizes[0];              // 100000
    const int E = in_sizes[7];              // 3200000
    const int L = in_sizes[3] / (DH * DH);  // 18 mid layers

    // workspace carve-up
    char* p = (char*)d_ws;
    double* dout_d = (double*)p; p += align256(sizeof(double) * N);
    double* din_d  = (double*)p; p += align256(sizeof(double) * N);
    double* x0     = (double*)p; p += align256(sizeof(double) * N);
    int* out_deg   = (int*)p;    p += align256(sizeof(int) * N);
    int* in_deg    = (int*)p;    p += align256(sizeof(int) * N);
    int* row_ptr   = (int*)p;    p += align256(sizeof(int) * (N + 1));
    int* cursor    = (int*)p;    p += align256(sizeof(int) * N);
    int* cs        = (int*)p;    p += align256(sizeof(int) * SCAN_CHUNKS);
    int* col       = (int*)p;    p += align256(sizeof(int) * E);
    float* xa      = (float*)p;  p += align256(sizeof(float) * N * DH);
    float* xb      = (float*)p;  p += align256(sizeof(float) * N * DH);

    const int BT = 256;
    int grid_n  = (N + BT - 1) / BT;
    int grid_e  = (E + BT - 1) / BT;
    int grid_nw = (N + 3) / 4;              // 1 wave per node, 4 waves per block
    int grid_ch = (SCAN_CHUNKS * 64 + BT - 1) / BT;   // 1 wave per chunk

    // ---- graph setup (identical work every call) ----
    hipMemsetAsync(out_deg, 0, sizeof(int) * N, stream);
    hipMemsetAsync(in_deg,  0, sizeof(int) * N, stream);
    count_deg<<<grid_e, BT, 0, stream>>>(src, dst, out_deg, in_deg, E);
    compute_norm<<<grid_n, BT, 0, stream>>>(out_deg, in_deg, dout_d, din_d, N);
    chunk_sums<<<grid_ch, BT, 0, stream>>>(in_deg, cs, N);
    scan_chunks<<<1, SCAN_CHUNKS, 0, stream>>>(cs);
    fill_rowptr<<<grid_ch, BT, 0, stream>>>(in_deg, cs, row_ptr, cursor, N, E);
    fill_csr<<<grid_e, BT, 0, stream>>>(src, dst, cursor, col, E);

    // ---- layer 0 (scalar input) ----
    compute_x0<<<grid_n, BT, 0, stream>>>(feat, dout_d, x0, N);
    layer_start<<<grid_nw, BT, 0, stream>>>(x0, row_ptr, col, din_d, dout_d,
                                            W_start, b_start, xa, N);

    // ---- 18 mid layers (ping-pong xa/xb) ----
    float* xin = xa;
    float* xot = xb;
    for (int l = 0; l < L; ++l) {
        layer_mid<<<grid_nw, BT, 0, stream>>>(xin, row_ptr, col, din_d, dout_d,
                                              W_mid + (size_t)l * DH * DH,
                                              b_mid + (size_t)l * DH, xot, N, 0);
        float* t = xin; xin = xot; xot = t;
    }

    // ---- final layer: raw store to d_out ----
    layer_mid<<<grid_nw, BT, 0, stream>>>(xin, row_ptr, col, din_d, dout_d,
                                          W_final, b_final, (float*)d_out, N, 1);
}